// Round 1
// baseline (754.384 us; speedup 1.0000x reference)
//
#include <hip/hip_runtime.h>
#include <stdint.h>

// ---- problem constants ----
#define D_MODEL  2048
#define N_INTER  1408
#define N_EXP    16
#define SH_INTER 2816
#define T_TOK    2048

typedef __attribute__((ext_vector_type(8))) short bf16x8;
typedef __attribute__((ext_vector_type(4))) float f32x4;

__device__ __forceinline__ unsigned short f2bf(float f){
  unsigned int b = __builtin_bit_cast(unsigned int, f);
  b = (b + 0x7FFFu + ((b >> 16) & 1u)) >> 16;   // RNE, inputs are finite
  return (unsigned short)b;
}

// ---------------- fp32 -> bf16 bulk convert ----------------
__global__ void cvt_bf16_kernel(const float* __restrict__ x,
                                unsigned short* __restrict__ o, int n4){
  const int i = blockIdx.x * blockDim.x + threadIdx.x;
  if (i >= n4) return;
  const float4 v = ((const float4*)x)[i];
  ushort4 u; u.x = f2bf(v.x); u.y = f2bf(v.y); u.z = f2bf(v.z); u.w = f2bf(v.w);
  ((ushort4*)o)[i] = u;
}

// ---------------- gate: softmax + group-limited top-k ----------------
// 1 wave (64 threads) per token. lane = expert(l&15) x quarter(l>>4).
__global__ void gate_kernel(const float* __restrict__ x, const float* __restrict__ Wg,
                            int* __restrict__ cnt, int* __restrict__ list,
                            float* __restrict__ wlist){
  const int t = blockIdx.x;
  const int l = threadIdx.x;
  const int e = l & 15, q = l >> 4;
  const float* xr = x + (size_t)t * D_MODEL + q * 512;
  const float* wr = Wg + (size_t)e * D_MODEL + q * 512;
  float p = 0.f;
  #pragma unroll 4
  for (int i = 0; i < 512; i += 4){
    float4 xv = *(const float4*)(xr + i);
    float4 wv = *(const float4*)(wr + i);
    p += xv.x*wv.x + xv.y*wv.y + xv.z*wv.z + xv.w*wv.w;
  }
  p += __shfl_xor(p, 16);
  p += __shfl_xor(p, 32);          // all lanes: full logit for expert e
  float mx = p;
  for (int d = 1; d < 16; d <<= 1) mx = fmaxf(mx, __shfl_xor(mx, d));
  float ex = __expf(p - mx);
  float sum = ex;
  for (int d = 1; d < 16; d <<= 1) sum += __shfl_xor(sum, d);
  const float sc = ex / sum;       // softmax score of expert e
  // group max (groups of 4 experts)
  float gm = fmaxf(sc, __shfl_xor(sc, 1));
  gm = fmaxf(gm, __shfl_xor(gm, 2));
  const float g0 = __shfl(gm, 0), g1 = __shfl(gm, 4),
              g2 = __shfl(gm, 8), g3 = __shfl(gm, 12);
  const int grp = e >> 2;
  const float gs[4] = {g0, g1, g2, g3};
  int grank = 0;
  #pragma unroll
  for (int j = 0; j < 4; ++j)
    if (gs[j] > gm || (gs[j] == gm && j < grp)) grank++;
  const float msc = (grank < 2) ? sc : -INFINITY;
  int erank = 0;
  #pragma unroll
  for (int j = 0; j < 16; ++j){
    const float oj = __shfl(msc, j);
    if (oj > msc || (oj == msc && j < e)) erank++;
  }
  if (q == 0 && erank < 4 && msc > -INFINITY){
    const int pos = atomicAdd(&cnt[e], 1);
    list[e * T_TOK + pos]  = (t << 2) | erank;   // slot = t*4+k
    wlist[e * T_TOK + pos] = sc;                 // ROUTE_SCALE = 1
  }
}

// ---------------- tiled bf16-MFMA GEMM ----------------
// MODE: 0 = shared gate/up (SwiGLU, bf16 out)   A=x_bf16  B1=Ws1 B3=Ws3
//       1 = routed gate/up (gathered rows)      A=x_bf16  B1=W1  B3=W3
//       2 = shared down (plain fp32 store)      A=Hs      B1=Ws2
//       3 = routed down (weight*val atomicAdd)  A=H       B1=W2
// Tile 128x128xBK32, 4 waves (2x2 of 64x64), 16x16x32 MFMA.
// B matrices are [N][K] row-major fp32; converted to bf16 during staging.
template<int MODE>
__global__ __launch_bounds__(256, 2)
void gemm_kernel(const unsigned short* __restrict__ A,
                 const float* __restrict__ B1,
                 const float* __restrict__ B3,
                 void* __restrict__ OutP,
                 const int* __restrict__ list,
                 const int* __restrict__ cnt,
                 const float* __restrict__ wlist,
                 int N, int K, int MT, int NT)
{
  constexpr bool GU     = (MODE == 0 || MODE == 1);
  constexpr bool GATHER = (MODE == 1 || MODE == 3);

  // +8 bf16 pad per row (stride 80B): <=2-way bank conflict on ds_read_b128 (free)
  __shared__ unsigned short As [128 * 40];
  __shared__ unsigned short Bs1[128 * 40];
  __shared__ unsigned short Bs3[GU ? 128 * 40 : 8];

  // XCD-chunked swizzle: consecutive same-XCD blocks walk m-tiles of one n-panel
  const int nb  = gridDim.x;            // divisible by 8 for all launches
  const int per = nb >> 3;
  const int gsw = (blockIdx.x & 7) * per + (blockIdx.x >> 3);
  const int mt   = gsw % MT;
  const int rest = gsw / MT;
  int nt, e;
  if (GATHER){ nt = rest % NT; e = rest / NT; } else { nt = rest; e = 0; }

  const int cntE = GATHER ? cnt[e] : (MT * 128);
  if (mt * 128 >= cntE) return;

  const size_t sB = (size_t)N * K;
  const float* b1 = B1 + (GATHER ? (size_t)e * sB : 0) + (size_t)(nt * 128) * K;
  const float* b3 = nullptr;
  if constexpr (GU) b3 = B3 + (GATHER ? (size_t)e * sB : 0) + (size_t)(nt * 128) * K;

  const int tid  = threadIdx.x;
  // A staging: 512 chunks of 16B (128 rows x 4 segs); thread does chunks tid, tid+256
  const int lrow = tid >> 2, seg0 = tid & 3;
  int arow0, arow1;
  if constexpr (GATHER){
    const int gr0 = mt * 128 + lrow, gr1 = gr0 + 64;
    const int p0 = min(gr0, cntE - 1), p1 = min(gr1, cntE - 1);
    const int e0 = list[e * T_TOK + p0], e1 = list[e * T_TOK + p1];
    arow0 = (MODE == 1) ? (e0 >> 2) : e0;
    arow1 = (MODE == 1) ? (e1 >> 2) : e1;
  } else { arow0 = mt * 128 + lrow; arow1 = arow0 + 64; }
  const unsigned short* pa0 = A + (size_t)arow0 * K + seg0 * 8;
  const unsigned short* pa1 = A + (size_t)arow1 * K + seg0 * 8;

  // B staging: 1024 chunks of float4 per matrix; thread does 4 (rows brow+32j)
  const int brow = tid >> 3, bseg = tid & 7;

  const int wid = tid >> 6, lane = tid & 63;
  const int wr = wid >> 1, wc = wid & 1;
  const int lr = lane & 15, lq = lane >> 4;

  f32x4 acc1[4][4];
  f32x4 acc3[GU ? 4 : 1][GU ? 4 : 1];
  const f32x4 zero = {0.f, 0.f, 0.f, 0.f};
  #pragma unroll
  for (int m = 0; m < 4; ++m)
    #pragma unroll
    for (int n = 0; n < 4; ++n){
      acc1[m][n] = zero;
      if constexpr (GU) acc3[m][n] = zero;
    }

  const int KT = K >> 5;
  for (int kt = 0; kt < KT; ++kt){
    const int k0 = kt << 5;
    __syncthreads();
    *(uint4*)(&As[lrow * 40 + seg0 * 8])        = *(const uint4*)(pa0 + k0);
    *(uint4*)(&As[(lrow + 64) * 40 + seg0 * 8]) = *(const uint4*)(pa1 + k0);
    #pragma unroll
    for (int j = 0; j < 4; ++j){
      const int row = brow + j * 32;
      const float4 v = *(const float4*)(b1 + (size_t)row * K + k0 + bseg * 4);
      ushort4 u; u.x = f2bf(v.x); u.y = f2bf(v.y); u.z = f2bf(v.z); u.w = f2bf(v.w);
      *(ushort4*)(&Bs1[row * 40 + bseg * 4]) = u;
      if constexpr (GU){
        const float4 w = *(const float4*)(b3 + (size_t)row * K + k0 + bseg * 4);
        ushort4 u3; u3.x = f2bf(w.x); u3.y = f2bf(w.y); u3.z = f2bf(w.z); u3.w = f2bf(w.w);
        *(ushort4*)(&Bs3[row * 40 + bseg * 4]) = u3;
      }
    }
    __syncthreads();

    bf16x8 af[4];
    #pragma unroll
    for (int m = 0; m < 4; ++m)
      af[m] = *(const bf16x8*)(&As[(wr * 64 + m * 16 + lr) * 40 + lq * 8]);
    #pragma unroll
    for (int n = 0; n < 4; ++n){
      const bf16x8 b1f = *(const bf16x8*)(&Bs1[(wc * 64 + n * 16 + lr) * 40 + lq * 8]);
      #pragma unroll
      for (int m = 0; m < 4; ++m)
        acc1[m][n] = __builtin_amdgcn_mfma_f32_16x16x32_bf16(af[m], b1f, acc1[m][n], 0, 0, 0);
      if constexpr (GU){
        const bf16x8 b3f = *(const bf16x8*)(&Bs3[(wc * 64 + n * 16 + lr) * 40 + lq * 8]);
        #pragma unroll
        for (int m = 0; m < 4; ++m)
          acc3[m][n] = __builtin_amdgcn_mfma_f32_16x16x32_bf16(af[m], b3f, acc3[m][n], 0, 0, 0);
      }
    }
  }

  // epilogue: C/D layout col = lane&15, row = (lane>>4)*4 + reg  [m89/m91]
  float* Outf = (float*)OutP;
  unsigned short* Outh = (unsigned short*)OutP;
  #pragma unroll
  for (int m = 0; m < 4; ++m){
    #pragma unroll
    for (int r = 0; r < 4; ++r){
      const int grow = mt * 128 + wr * 64 + m * 16 + lq * 4 + r;
      int outrow; float wgt = 1.f; bool valid = true;
      if constexpr (GATHER){
        valid = grow < cntE;
        const int p = min(grow, cntE - 1);
        const int entry = list[e * T_TOK + p];
        if constexpr (MODE == 1) outrow = entry;              // H slot
        else { outrow = entry >> 2; wgt = wlist[e * T_TOK + p]; }  // token row
      } else outrow = grow;
      if (!valid) continue;
      #pragma unroll
      for (int n = 0; n < 4; ++n){
        const int col = nt * 128 + wc * 64 + n * 16 + lr;
        if constexpr (GU){
          const float gv = acc1[m][n][r];
          const float uv = acc3[m][n][r];
          const float h = gv / (1.f + __expf(-gv)) * uv;      // silu(g)*u
          Outh[(size_t)outrow * N + col] = f2bf(h);
        } else if constexpr (MODE == 2){
          Outf[(size_t)outrow * N + col] = acc1[m][n][r];
        } else {
          atomicAdd(&Outf[(size_t)outrow * N + col], acc1[m][n][r] * wgt);
        }
      }
    }
  }
}

extern "C" void kernel_launch(void* const* d_in, const int* in_sizes, int n_in,
                              void* d_out, int out_size, void* d_ws, size_t ws_size,
                              hipStream_t stream)
{
  const float* x   = (const float*)d_in[0];
  const float* Wg  = (const float*)d_in[1];
  const float* W1  = (const float*)d_in[2];
  const float* W3  = (const float*)d_in[3];
  const float* W2  = (const float*)d_in[4];
  const float* Ws1 = (const float*)d_in[5];
  const float* Ws3 = (const float*)d_in[6];
  const float* Ws2 = (const float*)d_in[7];
  float* out = (float*)d_out;

  char* ws = (char*)d_ws;
  int*            cnt   = (int*)ws;                          // 16 ints
  int*            list  = (int*)(ws + 4096);                 // 16*2048 ints
  float*          wlist = (float*)(ws + 4096 + 16*T_TOK*4);  // 16*2048 floats
  unsigned short* xbf   = (unsigned short*)(ws + (size_t)(1  << 20));  // 8.39 MB
  unsigned short* Hs    = (unsigned short*)(ws + (size_t)(9  << 20));  // 11.5 MB
  unsigned short* H     = (unsigned short*)(ws + (size_t)(20 << 20));  // 23.1 MB

  hipMemsetAsync(cnt, 0, 4096, stream);
  cvt_bf16_kernel<<<(T_TOK * D_MODEL / 4) / 256, 256, 0, stream>>>(x, xbf, T_TOK * D_MODEL / 4);
  gate_kernel<<<T_TOK, 64, 0, stream>>>(x, Wg, cnt, list, wlist);

  // shared gate/up:  M=2048 N=2816 K=2048  -> Hs
  gemm_kernel<0><<<16 * 22, 256, 0, stream>>>(xbf, Ws1, Ws3, Hs,
                                              nullptr, nullptr, nullptr,
                                              SH_INTER, D_MODEL, 16, 22);
  // shared down:     M=2048 N=2048 K=2816  -> out (plain store, initializes out)
  gemm_kernel<2><<<16 * 16, 256, 0, stream>>>(Hs, Ws2, nullptr, out,
                                              nullptr, nullptr, nullptr,
                                              D_MODEL, SH_INTER, 16, 16);
  // routed gate/up:  per-expert gathered rows -> H[slot]
  gemm_kernel<1><<<16 * 11 * 16, 256, 0, stream>>>(xbf, W1, W3, H,
                                                   list, cnt, nullptr,
                                                   N_INTER, D_MODEL, 16, 11);
  // routed down:     H[slot] @ W2^T * weight -> atomicAdd out
  gemm_kernel<3><<<16 * 16 * 16, 256, 0, stream>>>(H, W2, nullptr, out,
                                                   list, cnt, wlist,
                                                   D_MODEL, N_INTER, 16, 16);
}